// Round 1
// baseline (334.332 us; speedup 1.0000x reference)
//
#include <hip/hip_runtime.h>

typedef unsigned short u16;
typedef unsigned int   u32;
typedef __attribute__((ext_vector_type(4))) float  f32x4;
typedef __attribute__((ext_vector_type(8))) __bf16 bf16x8;

#define B_    4096
#define D_    1024
#define K_    3000
#define KP    3072
#define INV_T 10.0f
#define INV_E 20.0f

__device__ __forceinline__ float bf2f(u32 bits16) {
    return __uint_as_float(bits16 << 16);
}
__device__ __forceinline__ u16 f2bf(float f) {  // round-to-nearest-even
    u32 u = __float_as_uint(f);
    u32 r = (u + 0x7fffu + ((u >> 16) & 1u)) >> 16;
    return (u16)r;
}
__device__ __forceinline__ void unpack8(uint4 v, float f[8]) {
    f[0] = __uint_as_float(v.x << 16); f[1] = __uint_as_float(v.x & 0xffff0000u);
    f[2] = __uint_as_float(v.y << 16); f[3] = __uint_as_float(v.y & 0xffff0000u);
    f[4] = __uint_as_float(v.z << 16); f[5] = __uint_as_float(v.z & 0xffff0000u);
    f[6] = __uint_as_float(v.w << 16); f[7] = __uint_as_float(v.w & 0xffff0000u);
}

#define GLDS(g, l) __builtin_amdgcn_global_load_lds( \
    (const __attribute__((address_space(1))) void*)(g), \
    (__attribute__((address_space(3))) void*)(l), 16, 0, 0)

// ---------------------------------------------------------------------------
// f32 -> bf16 conversion; W padded to KP rows with zeros.
// ---------------------------------------------------------------------------
__global__ __launch_bounds__(256) void convert_kernel(
    const float* __restrict__ z1, const float* __restrict__ z2,
    const float* __restrict__ W,
    u16* __restrict__ A1, u16* __restrict__ A2, u16* __restrict__ Wb)
{
    const int idx = blockIdx.x * 256 + threadIdx.x;
    const int n1 = B_ * D_ / 4;        // 1048576 float4 chunks per z
    const int nW = KP * D_ / 4;        // 786432 chunks of padded W
    ushort4 o;
    if (idx < n1) {
        float4 v = ((const float4*)z1)[idx];
        o.x = f2bf(v.x); o.y = f2bf(v.y); o.z = f2bf(v.z); o.w = f2bf(v.w);
        ((ushort4*)A1)[idx] = o;
    } else if (idx < 2 * n1) {
        const int j = idx - n1;
        float4 v = ((const float4*)z2)[j];
        o.x = f2bf(v.x); o.y = f2bf(v.y); o.z = f2bf(v.z); o.w = f2bf(v.w);
        ((ushort4*)A2)[j] = o;
    } else {
        const int j = idx - 2 * n1;
        if (j < nW) {
            const int row = j >> 8;    // (j*4)/1024
            if (row < K_) {
                float4 v = ((const float4*)W)[j];
                o.x = f2bf(v.x); o.y = f2bf(v.y); o.z = f2bf(v.z); o.w = f2bf(v.w);
            } else {
                o.x = 0; o.y = 0; o.z = 0; o.w = 0;
            }
            ((ushort4*)Wb)[j] = o;
        }
    }
}

// ---------------------------------------------------------------------------
// scores = z @ W^T  (both operands K-contiguous -> identical frag addressing).
// 128x128 tile, BK=32, 4 waves (2x2), 4x4 16x16x32 frags per wave.
// Fused epilogue: bf16 score store, colsum0_j = sum_i e^{s/eps} (u=1 pass),
// rowT_i = sum_{j<K} e^{s/T} (for lse).
// ---------------------------------------------------------------------------
__global__ __launch_bounds__(256) void gemm_kernel(
    const u16* __restrict__ A1, const u16* __restrict__ A2,
    const u16* __restrict__ Wb,
    u16* __restrict__ S1, u16* __restrict__ S2,
    float* __restrict__ cs0_1, float* __restrict__ cs0_2,
    float* __restrict__ rowT1, float* __restrict__ rowT2)
{
    const int mat = blockIdx.z;
    const u16* A  = mat ? A2 : A1;
    u16* S        = mat ? S2 : S1;
    float* csum   = mat ? cs0_2 : cs0_1;
    float* rowT   = mat ? rowT2 : rowT1;
    const int bm = blockIdx.y, bn = blockIdx.x;

    __shared__ u16 At[128 * 32];
    __shared__ u16 Bt[128 * 32];
    __shared__ float sCol[128];
    __shared__ float sRow[128];

    const int tid  = threadIdx.x;
    const int wid  = tid >> 6, lane = tid & 63;
    const int wr   = wid >> 1, wc = wid & 1;

    f32x4 acc[4][4];
#pragma unroll
    for (int m = 0; m < 4; ++m)
#pragma unroll
        for (int n = 0; n < 4; ++n) {
            f32x4 z = {0.f, 0.f, 0.f, 0.f};
            acc[m][n] = z;
        }

    // staging: lane l writes LDS base+l*16B -> row=lane>>2 (64B rows), col=(lane&3)*8 elems
    const int srow = lane >> 2, scol = (lane & 3) * 8;
    const u16* Ag = A  + (size_t)(bm * 128 + wid * 16 + srow) * D_ + scol;
    const u16* Bg = Wb + (size_t)(bn * 128 + wid * 16 + srow) * D_ + scol;
    u16* Al = At + wid * 16 * 32;
    u16* Bl = Bt + wid * 16 * 32;

    for (int kt = 0; kt < D_ / 32; ++kt) {
        const int ko = kt * 32;
        GLDS(Ag + ko,            Al);
        GLDS(Ag + 64 * D_ + ko,  Al + 64 * 32);
        GLDS(Bg + ko,            Bl);
        GLDS(Bg + 64 * D_ + ko,  Bl + 64 * 32);
        __syncthreads();   // drains vmcnt -> LDS tiles complete

        const u16* ar = At + (wr * 64 + (lane & 15)) * 32 + (lane >> 4) * 8;
        const u16* br = Bt + (wc * 64 + (lane & 15)) * 32 + (lane >> 4) * 8;
        bf16x8 a[4], b[4];
#pragma unroll
        for (int m = 0; m < 4; ++m) a[m] = *reinterpret_cast<const bf16x8*>(ar + m * 16 * 32);
#pragma unroll
        for (int n = 0; n < 4; ++n) b[n] = *reinterpret_cast<const bf16x8*>(br + n * 16 * 32);
#pragma unroll
        for (int m = 0; m < 4; ++m)
#pragma unroll
            for (int n = 0; n < 4; ++n)
                acc[m][n] = __builtin_amdgcn_mfma_f32_16x16x32_bf16(a[m], b[n], acc[m][n], 0, 0, 0);
        __syncthreads();   // LDS reads done before next overwrite
    }

    // ---- store scores as bf16 (C/D map: col=lane&15, row=(lane>>4)*4+r) ----
    const int lrow = wr * 64 + (lane >> 4) * 4;
    const int lcol = wc * 64 + (lane & 15);
#pragma unroll
    for (int m = 0; m < 4; ++m)
#pragma unroll
        for (int r = 0; r < 4; ++r) {
            u16* sp = S + (size_t)(bm * 128 + lrow + m * 16 + r) * KP + bn * 128 + lcol;
#pragma unroll
            for (int n = 0; n < 4; ++n) sp[n * 16] = f2bf(acc[m][n][r]);
        }

    // ---- fused reductions ----
    if (tid < 128) { sCol[tid] = 0.f; sRow[tid] = 0.f; }
    __syncthreads();

#pragma unroll
    for (int n = 0; n < 4; ++n) {
        float cs = 0.f;
#pragma unroll
        for (int m = 0; m < 4; ++m)
#pragma unroll
            for (int r = 0; r < 4; ++r) cs += __expf(acc[m][n][r] * INV_E);
        atomicAdd(&sCol[wc * 64 + n * 16 + (lane & 15)], cs);
    }

    const int gcol0 = bn * 128 + wc * 64 + (lane & 15);
#pragma unroll
    for (int m = 0; m < 4; ++m)
#pragma unroll
        for (int r = 0; r < 4; ++r) {
            float rs = 0.f;
#pragma unroll
            for (int n = 0; n < 4; ++n)
                if (gcol0 + n * 16 < K_) rs += __expf(acc[m][n][r] * INV_T);
            rs += __shfl_xor(rs, 1); rs += __shfl_xor(rs, 2);
            rs += __shfl_xor(rs, 4); rs += __shfl_xor(rs, 8);
            if ((lane & 15) == 0)
                atomicAdd(&sRow[wr * 64 + m * 16 + (lane >> 4) * 4 + r], rs);
        }
    __syncthreads();
    if (tid < 128) {
        atomicAdd(&csum[bn * 128 + tid], sCol[tid]);
        atomicAdd(&rowT[bm * 128 + tid], sRow[tid]);
    }
}

// ---------------------------------------------------------------------------
// row pass: u_i = 1/(B * sum_{j<K} e^{s_ij/eps} * v_j), v_j = 1/(K*colsum_j).
// One wave per row.
// ---------------------------------------------------------------------------
__global__ __launch_bounds__(256) void rowpass_kernel(
    const u16* __restrict__ S1, const u16* __restrict__ S2,
    const float* __restrict__ csA, const float* __restrict__ csB,
    float* __restrict__ u1, float* __restrict__ u2)
{
    const int mat = blockIdx.z;
    const u16* S   = mat ? S2 : S1;
    const float* cs = mat ? csB : csA;
    float* u       = mat ? u2 : u1;

    const int row  = blockIdx.x * 4 + (threadIdx.x >> 6);
    const int lane = threadIdx.x & 63;
    const uint4* sr = (const uint4*)(S + (size_t)row * KP);

    float acc = 0.f;
    for (int c = lane; c < K_ / 8; c += 64) {   // 375 chunks of 8 (K_ = 3000)
        uint4 v = sr[c];
        float f[8]; unpack8(v, f);
        const int j0 = c * 8;
#pragma unroll
        for (int e = 0; e < 8; ++e)
            acc += __expf(f[e] * INV_E) * __builtin_amdgcn_rcpf(3000.f * cs[j0 + e]);
    }
#pragma unroll
    for (int m = 1; m < 64; m <<= 1) acc += __shfl_xor(acc, m);
    if (lane == 0) u[row] = 1.f / (4096.f * acc);
}

// ---------------------------------------------------------------------------
// col pass: colsum_j = sum_i e^{s_ij/eps} * u_i. Thread owns 8 columns.
// ---------------------------------------------------------------------------
__global__ __launch_bounds__(256) void colpass_kernel(
    const u16* __restrict__ S1, const u16* __restrict__ S2,
    const float* __restrict__ u1, const float* __restrict__ u2,
    float* __restrict__ csA, float* __restrict__ csB)
{
    const int mat = blockIdx.z;
    const u16* S  = mat ? S2 : S1;
    const float* u = mat ? u2 : u1;
    float* cs     = mat ? csB : csA;

    const int c0 = blockIdx.x * 2048 + threadIdx.x * 8;
    if (c0 >= KP) return;
    float part[8] = {0.f, 0.f, 0.f, 0.f, 0.f, 0.f, 0.f, 0.f};
    const int r0 = blockIdx.y * 64;
    for (int i = r0; i < r0 + 64; ++i) {
        const float ui = u[i];
        uint4 v = *(const uint4*)(S + (size_t)i * KP + c0);
        float f[8]; unpack8(v, f);
#pragma unroll
        for (int e = 0; e < 8; ++e) part[e] += __expf(f[e] * INV_E) * ui;
    }
#pragma unroll
    for (int e = 0; e < 8; ++e) atomicAdd(&cs[c0 + e], part[e]);
}

// ---------------------------------------------------------------------------
// cross pass: cross[0] = sum q2*s1, cross[1] = sum q1*s2.
// q_ij = e^{s_ij/eps} * v_j * u_i with v_j = 1/(K*colsum3_j).
// ---------------------------------------------------------------------------
__global__ __launch_bounds__(256) void finalpass_kernel(
    const u16* __restrict__ S1, const u16* __restrict__ S2,
    const float* __restrict__ cs3_1, const float* __restrict__ cs3_2,
    const float* __restrict__ u1, const float* __restrict__ u2,
    float* __restrict__ cross)
{
    const int c0 = blockIdx.x * 2048 + threadIdx.x * 8;
    float a1 = 0.f, a2 = 0.f;
    if (c0 < K_) {
        float v1[8], v2[8];
#pragma unroll
        for (int e = 0; e < 8; ++e) {
            const int c = c0 + e;
            const bool ok = c < K_;
            v1[e] = ok ? __builtin_amdgcn_rcpf(3000.f * cs3_1[c]) : 0.f;
            v2[e] = ok ? __builtin_amdgcn_rcpf(3000.f * cs3_2[c]) : 0.f;
        }
        const int r0 = blockIdx.y * 64;
        for (int i = r0; i < r0 + 64; ++i) {
            const float u1i = u1[i], u2i = u2[i];
            uint4 va = *(const uint4*)(S1 + (size_t)i * KP + c0);
            uint4 vb = *(const uint4*)(S2 + (size_t)i * KP + c0);
            float f1[8], f2[8]; unpack8(va, f1); unpack8(vb, f2);
#pragma unroll
            for (int e = 0; e < 8; ++e) {
                const float q2 = __expf(f2[e] * INV_E) * v2[e] * u2i;
                const float q1 = __expf(f1[e] * INV_E) * v1[e] * u1i;
                a1 += q2 * f1[e];
                a2 += q1 * f2[e];
            }
        }
    }
#pragma unroll
    for (int m = 1; m < 64; m <<= 1) { a1 += __shfl_xor(a1, m); a2 += __shfl_xor(a2, m); }
    __shared__ float sa[4], sb[4];
    const int wid = threadIdx.x >> 6, lane = threadIdx.x & 63;
    if (lane == 0) { sa[wid] = a1; sb[wid] = a2; }
    __syncthreads();
    if (threadIdx.x == 0) {
        atomicAdd(&cross[0], sa[0] + sa[1] + sa[2] + sa[3]);
        atomicAdd(&cross[1], sb[0] + sb[1] + sb[2] + sb[3]);
    }
}

// ---------------------------------------------------------------------------
// finisher: loss = -0.5*[ (cross1+cross2)/(B*T) - (sum lse1 + sum lse2)/B^2 ]
// ---------------------------------------------------------------------------
__global__ __launch_bounds__(256) void finisher_kernel(
    const float* __restrict__ rowT1, const float* __restrict__ rowT2,
    const float* __restrict__ cross, float* __restrict__ out)
{
    float l = 0.f;
    for (int i = threadIdx.x; i < B_; i += 256)
        l += logf(rowT1[i]) + logf(rowT2[i]);
#pragma unroll
    for (int m = 1; m < 64; m <<= 1) l += __shfl_xor(l, m);
    __shared__ float s[4];
    if ((threadIdx.x & 63) == 0) s[threadIdx.x >> 6] = l;
    __syncthreads();
    if (threadIdx.x == 0) {
        const float sumlse = s[0] + s[1] + s[2] + s[3];
        const float t = (cross[0] + cross[1]) * (1.0f / (4096.0f * 0.1f));
        const float term = t - sumlse * (1.0f / (4096.0f * 4096.0f));
        out[0] = -0.5f * term;
    }
}

// ---------------------------------------------------------------------------
extern "C" void kernel_launch(void* const* d_in, const int* in_sizes, int n_in,
                              void* d_out, int out_size, void* d_ws, size_t ws_size,
                              hipStream_t stream)
{
    const float* z1 = (const float*)d_in[0];
    const float* z2 = (const float*)d_in[1];
    const float* W  = (const float*)d_in[2];
    float* out = (float*)d_out;

    char* p = (char*)d_ws;
    u16* A1 = (u16*)p; p += (size_t)B_ * D_ * 2;
    u16* A2 = (u16*)p; p += (size_t)B_ * D_ * 2;
    u16* Wb = (u16*)p; p += (size_t)KP * D_ * 2;
    u16* S1 = (u16*)p; p += (size_t)B_ * KP * 2;
    u16* S2 = (u16*)p; p += (size_t)B_ * KP * 2;
    float* cs0_1 = (float*)p; p += KP * 4;
    float* cs2_1 = (float*)p; p += KP * 4;
    float* cs3_1 = (float*)p; p += KP * 4;
    float* cs0_2 = (float*)p; p += KP * 4;
    float* cs2_2 = (float*)p; p += KP * 4;
    float* cs3_2 = (float*)p; p += KP * 4;
    float* rowT1 = (float*)p; p += B_ * 4;
    float* rowT2 = (float*)p; p += B_ * 4;
    float* cross = (float*)p; p += 16 * 4;
    float* u1 = (float*)p; p += B_ * 4;
    float* u2 = (float*)p; p += B_ * 4;

    // zero all atomic accumulators (cs0..cs3, rowT, cross) in one memset
    const size_t zbytes = 6 * KP * 4 + 2 * B_ * 4 + 16 * 4;
    hipMemsetAsync(cs0_1, 0, zbytes, stream);

    convert_kernel<<<11264, 256, 0, stream>>>(z1, z2, W, A1, A2, Wb);

    gemm_kernel<<<dim3(KP / 128, B_ / 128, 2), 256, 0, stream>>>(
        A1, A2, Wb, S1, S2, cs0_1, cs0_2, rowT1, rowT2);

    // sinkhorn: (col,row) x3; first col fused in GEMM epilogue (u=1)
    rowpass_kernel<<<dim3(B_ / 4, 1, 2), 256, 0, stream>>>(S1, S2, cs0_1, cs0_2, u1, u2);
    colpass_kernel<<<dim3(2, 64, 2), 256, 0, stream>>>(S1, S2, u1, u2, cs2_1, cs2_2);
    rowpass_kernel<<<dim3(B_ / 4, 1, 2), 256, 0, stream>>>(S1, S2, cs2_1, cs2_2, u1, u2);
    colpass_kernel<<<dim3(2, 64, 2), 256, 0, stream>>>(S1, S2, u1, u2, cs3_1, cs3_2);
    rowpass_kernel<<<dim3(B_ / 4, 1, 2), 256, 0, stream>>>(S1, S2, cs3_1, cs3_2, u1, u2);

    finalpass_kernel<<<dim3(2, 64, 1), 256, 0, stream>>>(S1, S2, cs3_1, cs3_2, u1, u2, cross);
    finisher_kernel<<<1, 256, 0, stream>>>(rowT1, rowT2, cross, out);
}

// Round 3
// 260.768 us; speedup vs baseline: 1.2821x; 1.2821x over previous
//
#include <hip/hip_runtime.h>

typedef unsigned short u16;
typedef unsigned int   u32;
typedef __attribute__((ext_vector_type(4))) float  f32x4;
typedef __attribute__((ext_vector_type(8))) __bf16 bf16x8;

#define B_    4096
#define D_    1024
#define K_    3000
#define KP    3072
#define INV_T 10.0f
#define INV_E 20.0f

__device__ __forceinline__ u16 f2bf(float f) {  // round-to-nearest-even
    u32 u = __float_as_uint(f);
    u32 r = (u + 0x7fffu + ((u >> 16) & 1u)) >> 16;
    return (u16)r;
}
__device__ __forceinline__ void unpack8(uint4 v, float f[8]) {
    f[0] = __uint_as_float(v.x << 16); f[1] = __uint_as_float(v.x & 0xffff0000u);
    f[2] = __uint_as_float(v.y << 16); f[3] = __uint_as_float(v.y & 0xffff0000u);
    f[4] = __uint_as_float(v.z << 16); f[5] = __uint_as_float(v.z & 0xffff0000u);
    f[6] = __uint_as_float(v.w << 16); f[7] = __uint_as_float(v.w & 0xffff0000u);
}

#define GLDS(g, l) __builtin_amdgcn_global_load_lds( \
    (const __attribute__((address_space(1))) void*)(g), \
    (__attribute__((address_space(3))) void*)(l), 16, 0, 0)

// ---------------------------------------------------------------------------
// f32 -> bf16 conversion; W padded to KP rows with zeros.
// ---------------------------------------------------------------------------
__global__ __launch_bounds__(256) void convert_kernel(
    const float* __restrict__ z1, const float* __restrict__ z2,
    const float* __restrict__ W,
    u16* __restrict__ A1, u16* __restrict__ A2, u16* __restrict__ Wb)
{
    const int idx = blockIdx.x * 256 + threadIdx.x;
    const int n1 = B_ * D_ / 4;
    const int nW = KP * D_ / 4;
    ushort4 o;
    if (idx < n1) {
        float4 v = ((const float4*)z1)[idx];
        o.x = f2bf(v.x); o.y = f2bf(v.y); o.z = f2bf(v.z); o.w = f2bf(v.w);
        ((ushort4*)A1)[idx] = o;
    } else if (idx < 2 * n1) {
        const int j = idx - n1;
        float4 v = ((const float4*)z2)[j];
        o.x = f2bf(v.x); o.y = f2bf(v.y); o.z = f2bf(v.z); o.w = f2bf(v.w);
        ((ushort4*)A2)[j] = o;
    } else {
        const int j = idx - 2 * n1;
        if (j < nW) {
            const int row = j >> 8;
            if (row < K_) {
                float4 v = ((const float4*)W)[j];
                o.x = f2bf(v.x); o.y = f2bf(v.y); o.z = f2bf(v.z); o.w = f2bf(v.w);
            } else {
                o.x = 0; o.y = 0; o.z = 0; o.w = 0;
            }
            ((ushort4*)Wb)[j] = o;
        }
    }
}

// ---------------------------------------------------------------------------
// scores = z @ W^T. 128x128 tile, BK=64, 4 waves (2x2), 4x4 16x16x32 frags.
// LDS XOR-swizzle (rule #21): linear global_load_lds dest, source slot
// pre-swizzled (t&7)^(srow&7), read slot (kk*4+g)^(row&7) -> conflict-free.
// Fused epilogue: bf16 score store, colsum0_j = sum_i e^{s/eps} (u=1 pass),
// rowT_i = sum_{j<K} e^{s/T} (for lse).
// ---------------------------------------------------------------------------
__global__ __launch_bounds__(256) void gemm_kernel(
    const u16* __restrict__ A1, const u16* __restrict__ A2,
    const u16* __restrict__ Wb,
    u16* __restrict__ S1, u16* __restrict__ S2,
    float* __restrict__ cs0_1, float* __restrict__ cs0_2,
    float* __restrict__ rowT1, float* __restrict__ rowT2)
{
    const int mat = blockIdx.z;
    const u16* A  = mat ? A2 : A1;
    u16* S        = mat ? S2 : S1;
    float* csum   = mat ? cs0_2 : cs0_1;
    float* rowT   = mat ? rowT2 : rowT1;
    const int bm = blockIdx.y, bn = blockIdx.x;

    __shared__ u16 At[128 * 64];
    __shared__ u16 Bt[128 * 64];
    __shared__ float sCol[128];
    __shared__ float sRow[128];

    const int tid  = threadIdx.x;
    const int wid  = tid >> 6, lane = tid & 63;
    const int wr   = wid >> 1, wc = wid & 1;

    f32x4 acc[4][4];
#pragma unroll
    for (int m = 0; m < 4; ++m)
#pragma unroll
        for (int n = 0; n < 4; ++n) {
            f32x4 z = {0.f, 0.f, 0.f, 0.f};
            acc[m][n] = z;
        }

    // staging geometry: thread t writes LDS row (r*32 + t>>3), elem slot t&7.
    // Source slot pre-swizzled so swizzled reads see correct data.
    const int srow  = tid >> 3;                   // 0..31
    const int sslot = (tid & 7) ^ (srow & 7);     // swizzled source 16B slot
    const u16* Aga[4]; const u16* Bga[4]; u16* Ald[4]; u16* Bld[4];
#pragma unroll
    for (int r = 0; r < 4; ++r) {
        Aga[r] = A  + (size_t)(bm * 128 + r * 32 + srow) * D_ + sslot * 8;
        Bga[r] = Wb + (size_t)(bn * 128 + r * 32 + srow) * D_ + sslot * 8;
        Ald[r] = At + (r * 32 + srow) * 64 + (tid & 7) * 8;
        Bld[r] = Bt + (r * 32 + srow) * 64 + (tid & 7) * 8;
    }

    const int r15 = lane & 15, g = lane >> 4;
    const int sw0 = (g ^ (r15 & 7)) * 8;          // kk=0 swizzled elem offset
    const int sw1 = ((g ^ (r15 & 7)) ^ 4) * 8;    // kk=1
    const u16* arow = At + (wr * 64 + r15) * 64;
    const u16* brow = Bt + (wc * 64 + r15) * 64;

    for (int kt = 0; kt < D_ / 64; ++kt) {
        const int ko = kt * 64;
#pragma unroll
        for (int r = 0; r < 4; ++r) {
            GLDS(Aga[r] + ko, Ald[r]);
            GLDS(Bga[r] + ko, Bld[r]);
        }
        __syncthreads();   // drains vmcnt -> LDS tiles complete

        bf16x8 a[4], b[4];
#pragma unroll
        for (int m = 0; m < 4; ++m) a[m] = *reinterpret_cast<const bf16x8*>(arow + m * 16 * 64 + sw0);
#pragma unroll
        for (int n = 0; n < 4; ++n) b[n] = *reinterpret_cast<const bf16x8*>(brow + n * 16 * 64 + sw0);
#pragma unroll
        for (int m = 0; m < 4; ++m)
#pragma unroll
            for (int n = 0; n < 4; ++n)
                acc[m][n] = __builtin_amdgcn_mfma_f32_16x16x32_bf16(a[m], b[n], acc[m][n], 0, 0, 0);
#pragma unroll
        for (int m = 0; m < 4; ++m) a[m] = *reinterpret_cast<const bf16x8*>(arow + m * 16 * 64 + sw1);
#pragma unroll
        for (int n = 0; n < 4; ++n) b[n] = *reinterpret_cast<const bf16x8*>(brow + n * 16 * 64 + sw1);
#pragma unroll
        for (int m = 0; m < 4; ++m)
#pragma unroll
            for (int n = 0; n < 4; ++n)
                acc[m][n] = __builtin_amdgcn_mfma_f32_16x16x32_bf16(a[m], b[n], acc[m][n], 0, 0, 0);
        __syncthreads();   // LDS reads done before next overwrite
    }

    // ---- store scores as bf16 (C/D map: col=lane&15, row=(lane>>4)*4+r) ----
    const int lrow = wr * 64 + (lane >> 4) * 4;
    const int lcol = wc * 64 + (lane & 15);
#pragma unroll
    for (int m = 0; m < 4; ++m)
#pragma unroll
        for (int r = 0; r < 4; ++r) {
            u16* sp = S + (size_t)(bm * 128 + lrow + m * 16 + r) * KP + bn * 128 + lcol;
#pragma unroll
            for (int n = 0; n < 4; ++n) sp[n * 16] = f2bf(acc[m][n][r]);
        }

    // ---- fused reductions ----
    if (tid < 128) { sCol[tid] = 0.f; sRow[tid] = 0.f; }
    __syncthreads();

#pragma unroll
    for (int n = 0; n < 4; ++n) {
        float cs = 0.f;
#pragma unroll
        for (int m = 0; m < 4; ++m)
#pragma unroll
            for (int r = 0; r < 4; ++r) cs += __expf(acc[m][n][r] * INV_E);
        atomicAdd(&sCol[wc * 64 + n * 16 + (lane & 15)], cs);
    }

    const int gcol0 = bn * 128 + wc * 64 + (lane & 15);
#pragma unroll
    for (int m = 0; m < 4; ++m)
#pragma unroll
        for (int r = 0; r < 4; ++r) {
            float rs = 0.f;
#pragma unroll
            for (int n = 0; n < 4; ++n)
                if (gcol0 + n * 16 < K_) rs += __expf(acc[m][n][r] * INV_T);
            rs += __shfl_xor(rs, 1); rs += __shfl_xor(rs, 2);
            rs += __shfl_xor(rs, 4); rs += __shfl_xor(rs, 8);
            if ((lane & 15) == 0)
                atomicAdd(&sRow[wr * 64 + m * 16 + (lane >> 4) * 4 + r], rs);
        }
    __syncthreads();
    if (tid < 128) {
        atomicAdd(&csum[bn * 128 + tid], sCol[tid]);
        atomicAdd(&rowT[bm * 128 + tid], sRow[tid]);
    }
}

// ---------------------------------------------------------------------------
// row pass: u_i = 1/(B * sum_{j<K} e^{s_ij/eps} * v_j), v_j = 1/(K*colsum_j).
// One wave per row, fully unrolled 5 chunks + tail, float4 cs loads.
// ---------------------------------------------------------------------------
__global__ __launch_bounds__(256) void rowpass_kernel(
    const u16* __restrict__ S1, const u16* __restrict__ S2,
    const float* __restrict__ csA, const float* __restrict__ csB,
    float* __restrict__ u1, float* __restrict__ u2)
{
    const int mat = blockIdx.z;
    const u16* S    = mat ? S2 : S1;
    const float* cs = mat ? csB : csA;
    float* u        = mat ? u2 : u1;

    const int row  = blockIdx.x * 4 + (threadIdx.x >> 6);
    const int lane = threadIdx.x & 63;
    const uint4*  sr = (const uint4*)(S + (size_t)row * KP);
    const float4* cv = (const float4*)cs;

    float acc = 0.f;
#pragma unroll
    for (int k = 0; k < 5; ++k) {              // 5*64 = 320 full chunks
        const int c = lane + k * 64;
        uint4 v = sr[c];
        float4 ca = cv[2 * c], cb = cv[2 * c + 1];
        float f[8]; unpack8(v, f);
        acc += __expf(f[0] * INV_E) * __builtin_amdgcn_rcpf(3000.f * ca.x);
        acc += __expf(f[1] * INV_E) * __builtin_amdgcn_rcpf(3000.f * ca.y);
        acc += __expf(f[2] * INV_E) * __builtin_amdgcn_rcpf(3000.f * ca.z);
        acc += __expf(f[3] * INV_E) * __builtin_amdgcn_rcpf(3000.f * ca.w);
        acc += __expf(f[4] * INV_E) * __builtin_amdgcn_rcpf(3000.f * cb.x);
        acc += __expf(f[5] * INV_E) * __builtin_amdgcn_rcpf(3000.f * cb.y);
        acc += __expf(f[6] * INV_E) * __builtin_amdgcn_rcpf(3000.f * cb.z);
        acc += __expf(f[7] * INV_E) * __builtin_amdgcn_rcpf(3000.f * cb.w);
    }
    {
        const int c = 320 + lane;              // tail: chunks 320..374
        if (c < K_ / 8) {
            uint4 v = sr[c];
            float4 ca = cv[2 * c], cb = cv[2 * c + 1];
            float f[8]; unpack8(v, f);
            acc += __expf(f[0] * INV_E) * __builtin_amdgcn_rcpf(3000.f * ca.x);
            acc += __expf(f[1] * INV_E) * __builtin_amdgcn_rcpf(3000.f * ca.y);
            acc += __expf(f[2] * INV_E) * __builtin_amdgcn_rcpf(3000.f * ca.z);
            acc += __expf(f[3] * INV_E) * __builtin_amdgcn_rcpf(3000.f * ca.w);
            acc += __expf(f[4] * INV_E) * __builtin_amdgcn_rcpf(3000.f * cb.x);
            acc += __expf(f[5] * INV_E) * __builtin_amdgcn_rcpf(3000.f * cb.y);
            acc += __expf(f[6] * INV_E) * __builtin_amdgcn_rcpf(3000.f * cb.z);
            acc += __expf(f[7] * INV_E) * __builtin_amdgcn_rcpf(3000.f * cb.w);
        }
    }
#pragma unroll
    for (int m = 1; m < 64; m <<= 1) acc += __shfl_xor(acc, m);
    if (lane == 0) u[row] = 1.f / (4096.f * acc);
}

// ---------------------------------------------------------------------------
// col pass: colsum_j = sum_i e^{s_ij/eps} * u_i.
// 1536 blocks: 6 col-chunks x 128 row-chunks x 2 mats; wave covers 512 cols.
// ---------------------------------------------------------------------------
__global__ __launch_bounds__(256) void colpass_kernel(
    const u16* __restrict__ S1, const u16* __restrict__ S2,
    const float* __restrict__ u1, const float* __restrict__ u2,
    float* __restrict__ csA, float* __restrict__ csB)
{
    const int mat = blockIdx.z;
    const u16* S   = mat ? S2 : S1;
    const float* u = mat ? u2 : u1;
    float* cs      = mat ? csB : csA;

    const int tid = threadIdx.x;
    const int wid = tid >> 6, lane = tid & 63;
    const int c0  = blockIdx.x * 512 + lane * 8;   // < 3072
    const int r0  = blockIdx.y * 32;

    float part[8] = {0.f, 0.f, 0.f, 0.f, 0.f, 0.f, 0.f, 0.f};
#pragma unroll
    for (int rr = 0; rr < 8; ++rr) {
        const int i = r0 + wid + rr * 4;
        const float ui = u[i];
        uint4 v = *(const uint4*)(S + (size_t)i * KP + c0);
        float f[8]; unpack8(v, f);
#pragma unroll
        for (int e = 0; e < 8; ++e) part[e] += __expf(f[e] * INV_E) * ui;
    }

    __shared__ float red[4][512];
    float4* rp = (float4*)&red[wid][lane * 8];
    rp[0] = make_float4(part[0], part[1], part[2], part[3]);
    rp[1] = make_float4(part[4], part[5], part[6], part[7]);
    __syncthreads();
#pragma unroll
    for (int q = 0; q < 2; ++q) {
        const int cc = tid * 2 + q;
        const float s = red[0][cc] + red[1][cc] + red[2][cc] + red[3][cc];
        atomicAdd(&cs[blockIdx.x * 512 + cc], s);
    }
}

// ---------------------------------------------------------------------------
// fused row3 + cross pass. Per row i (wave-per-row):
//   t1 = sum_j e^{s1/eps} v1_j,  d1 = sum_j e^{s1/eps} v1_j * s2_ij
//   t2 = sum_j e^{s2/eps} v2_j,  d2 = sum_j e^{s2/eps} v2_j * s1_ij
// cross[0] += d2/(B*t2)   (= sum_j q2*s1 for this row)
// cross[1] += d1/(B*t1)
// ---------------------------------------------------------------------------
__global__ __launch_bounds__(256) void rowcross_kernel(
    const u16* __restrict__ S1, const u16* __restrict__ S2,
    const float* __restrict__ cs3_1, const float* __restrict__ cs3_2,
    float* __restrict__ cross)
{
    const int wid  = threadIdx.x >> 6, lane = threadIdx.x & 63;
    const int row  = blockIdx.x * 4 + wid;
    const uint4*  s1r = (const uint4*)(S1 + (size_t)row * KP);
    const uint4*  s2r = (const uint4*)(S2 + (size_t)row * KP);
    const float4* c1v = (const float4*)cs3_1;
    const float4* c2v = (const float4*)cs3_2;

    float t1 = 0.f, d1 = 0.f, t2 = 0.f, d2 = 0.f;
#pragma unroll
    for (int k = 0; k < 6; ++k) {
        const int c = lane + k * 64;
        if (k == 5 && c >= K_ / 8) break;
        uint4 va = s1r[c], vb = s2r[c];
        float4 p1a = c1v[2 * c], p1b = c1v[2 * c + 1];
        float4 p2a = c2v[2 * c], p2b = c2v[2 * c + 1];
        float f1[8], f2[8]; unpack8(va, f1); unpack8(vb, f2);
        const float w1[8] = {p1a.x, p1a.y, p1a.z, p1a.w, p1b.x, p1b.y, p1b.z, p1b.w};
        const float w2[8] = {p2a.x, p2a.y, p2a.z, p2a.w, p2b.x, p2b.y, p2b.z, p2b.w};
#pragma unroll
        for (int e = 0; e < 8; ++e) {
            const float e1 = __expf(f1[e] * INV_E) * __builtin_amdgcn_rcpf(3000.f * w1[e]);
            const float e2 = __expf(f2[e] * INV_E) * __builtin_amdgcn_rcpf(3000.f * w2[e]);
            t1 += e1; d1 += e1 * f2[e];
            t2 += e2; d2 += e2 * f1[e];
        }
    }
#pragma unroll
    for (int m = 1; m < 64; m <<= 1) {
        t1 += __shfl_xor(t1, m); d1 += __shfl_xor(d1, m);
        t2 += __shfl_xor(t2, m); d2 += __shfl_xor(d2, m);
    }
    __shared__ float sa[4], sb[4];
    if (lane == 0) {
        sa[wid] = d2 / (4096.f * t2);   // contribution to cross[0]
        sb[wid] = d1 / (4096.f * t1);   // contribution to cross[1]
    }
    __syncthreads();
    if (threadIdx.x == 0) {
        atomicAdd(&cross[0], sa[0] + sa[1] + sa[2] + sa[3]);
        atomicAdd(&cross[1], sb[0] + sb[1] + sb[2] + sb[3]);
    }
}

// ---------------------------------------------------------------------------
// finisher: loss = -0.5*[ (cross1+cross2)/(B*T) - (sum lse1 + sum lse2)/B^2 ]
// ---------------------------------------------------------------------------
__global__ __launch_bounds__(256) void finisher_kernel(
    const float* __restrict__ rowT1, const float* __restrict__ rowT2,
    const float* __restrict__ cross, float* __restrict__ out)
{
    float l = 0.f;
    for (int i = threadIdx.x; i < B_; i += 256)
        l += logf(rowT1[i]) + logf(rowT2[i]);
#pragma unroll
    for (int m = 1; m < 64; m <<= 1) l += __shfl_xor(l, m);
    __shared__ float s[4];
    if ((threadIdx.x & 63) == 0) s[threadIdx.x >> 6] = l;
    __syncthreads();
    if (threadIdx.x == 0) {
        const float sumlse = s[0] + s[1] + s[2] + s[3];
        const float t = (cross[0] + cross[1]) * (1.0f / (4096.0f * 0.1f));
        const float term = t - sumlse * (1.0f / (4096.0f * 4096.0f));
        out[0] = -0.5f * term;
    }
}

// ---------------------------------------------------------------------------
extern "C" void kernel_launch(void* const* d_in, const int* in_sizes, int n_in,
                              void* d_out, int out_size, void* d_ws, size_t ws_size,
                              hipStream_t stream)
{
    const float* z1 = (const float*)d_in[0];
    const float* z2 = (const float*)d_in[1];
    const float* W  = (const float*)d_in[2];
    float* out = (float*)d_out;

    char* p = (char*)d_ws;
    u16* A1 = (u16*)p; p += (size_t)B_ * D_ * 2;
    u16* A2 = (u16*)p; p += (size_t)B_ * D_ * 2;
    u16* Wb = (u16*)p; p += (size_t)KP * D_ * 2;
    u16* S1 = (u16*)p; p += (size_t)B_ * KP * 2;
    u16* S2 = (u16*)p; p += (size_t)B_ * KP * 2;
    float* cs0_1 = (float*)p; p += KP * 4;
    float* cs2_1 = (float*)p; p += KP * 4;
    float* cs3_1 = (float*)p; p += KP * 4;
    float* cs0_2 = (float*)p; p += KP * 4;
    float* cs2_2 = (float*)p; p += KP * 4;
    float* cs3_2 = (float*)p; p += KP * 4;
    float* rowT1 = (float*)p; p += B_ * 4;
    float* rowT2 = (float*)p; p += B_ * 4;
    float* cross = (float*)p; p += 16 * 4;
    float* u1 = (float*)p; p += B_ * 4;
    float* u2 = (float*)p; p += B_ * 4;

    // zero all atomic accumulators (cs0..cs3 x2, rowT x2, cross) in one memset
    const size_t zbytes = 6 * KP * 4 + 2 * B_ * 4 + 16 * 4;
    hipMemsetAsync(cs0_1, 0, zbytes, stream);

    convert_kernel<<<11264, 256, 0, stream>>>(z1, z2, W, A1, A2, Wb);

    gemm_kernel<<<dim3(KP / 128, B_ / 128, 2), 256, 0, stream>>>(
        A1, A2, Wb, S1, S2, cs0_1, cs0_2, rowT1, rowT2);

    // sinkhorn: col0 fused in GEMM (u=1); then row,col,row,col,row(+cross)
    rowpass_kernel<<<dim3(B_ / 4, 1, 2), 256, 0, stream>>>(S1, S2, cs0_1, cs0_2, u1, u2);
    colpass_kernel<<<dim3(6, 128, 2), 256, 0, stream>>>(S1, S2, u1, u2, cs2_1, cs2_2);
    rowpass_kernel<<<dim3(B_ / 4, 1, 2), 256, 0, stream>>>(S1, S2, cs2_1, cs2_2, u1, u2);
    colpass_kernel<<<dim3(6, 128, 2), 256, 0, stream>>>(S1, S2, u1, u2, cs3_1, cs3_2);

    rowcross_kernel<<<dim3(B_ / 4, 1, 1), 256, 0, stream>>>(S1, S2, cs3_1, cs3_2, cross);
    finisher_kernel<<<1, 256, 0, stream>>>(rowT1, rowT2, cross, out);
}